// Round 12
// baseline (4313.386 us; speedup 1.0000x reference)
//
#include <hip/hip_runtime.h>
#include <hip/hip_bf16.h>

// whole_network: attention -> corrcoef -> 5x (GCN + BatchNorm(node) + tanh) -> linear head
// B=8192, N=100 (pad 112), T=64.
// R12: concurrency restructure. KA = 4 phases, 53.2KB LDS, 3 blocks/CU (x direct from
// global, corr HBM-only). New KB0 does t0=x@W1^T + z1=corr@t0 (proven KB structure).
// KB layers slimmed to 40.8KB -> 4 blocks/CU.

typedef unsigned int u32;
typedef unsigned short u16;
typedef float f32x4 __attribute__((ext_vector_type(4)));
typedef short s16x8 __attribute__((ext_vector_type(8)));

__device__ __forceinline__ f32x4 mfma16(s16x8 a, s16x8 b, f32x4 c) {
  return __builtin_amdgcn_mfma_f32_16x16x32_bf16(a, b, c, 0, 0, 0);
}
__device__ __forceinline__ u16 f2b(float f) {
  __hip_bfloat16 h = __float2bfloat16(f);
  u16 u; __builtin_memcpy(&u, &h, 2); return u;
}
__device__ __forceinline__ float b2f(u16 u) { return __uint_as_float((u32)u << 16); }
__device__ __forceinline__ float blo(u32 u) { return __uint_as_float(u << 16); }
__device__ __forceinline__ float bhi(u32 u) { return __uint_as_float(u & 0xffff0000u); }
__device__ __forceinline__ float fast_tanh(float x) {
  float e = __expf(2.0f * x);
  return 1.0f - 2.0f * __builtin_amdgcn_rcpf(e + 1.0f);
}
// build hi/lo bf16 fragments from 8 f32 (global), zero if !ok
__device__ __forceinline__ void hilo8(const float* p, bool ok, s16x8& hi, s16x8& lo) {
  const float4* p4 = (const float4*)p;
  float4 a = {0.f,0.f,0.f,0.f}, b = {0.f,0.f,0.f,0.f};
  if (ok) { a = p4[0]; b = p4[1]; }
  float v[8] = {a.x,a.y,a.z,a.w,b.x,b.y,b.z,b.w};
#pragma unroll
  for (int e = 0; e < 8; ++e) {
    u16 hh = f2b(v[e]);
    hi[e] = (short)hh;
    lo[e] = (short)f2b(v[e] - b2f(hh));
  }
}

// ---------------- KA LDS map (BYTE offsets), total 54144 => 3 blocks/CU ----------------
// Q u16[112][36]@0 (8064) ; K @8064 (8064)          (P1-P2)
// chat_hi over Q, chat_lo over K                     (P3-P4)
// A u16[112][132]@16128 (29568)                      (P2-P3)
// Vt u16[32][132]@45696 (8448)                       (P1-P3)
#define KA_QS_B   0
#define KA_KS_B   8064
#define KA_CHH_B  0
#define KA_CHL_B  8064
#define KA_A_B    16128
#define KA_VT_B   45696
#define KA_SMEM_B 54144

__global__ __launch_bounds__(512, 6) void ka_kernel(
    const float* __restrict__ x,
    const float* __restrict__ Wq, const float* __restrict__ bq,
    const float* __restrict__ Wk, const float* __restrict__ bk,
    const float* __restrict__ Wv, const float* __restrict__ bv,
    __hip_bfloat16* __restrict__ corr_g)   // [B,100,100] bf16
{
  __shared__ __align__(16) char smem[KA_SMEM_B];
  u16* Qs  = (u16*)(smem + KA_QS_B);
  u16* Ks  = (u16*)(smem + KA_KS_B);
  u16* chh = (u16*)(smem + KA_CHH_B);
  u16* chl = (u16*)(smem + KA_CHL_B);
  u16* A16 = (u16*)(smem + KA_A_B);
  u16* Vt  = (u16*)(smem + KA_VT_B);

  const int b = blockIdx.x, tid = threadIdx.x;
  const int w = tid >> 6, l15 = tid & 15, g = (tid & 63) >> 4;
  const f32x4 zero4 = {0.f, 0.f, 0.f, 0.f};

  // zero Vt pad rows (m = 112..127 of each of 32 cols j)
  if (tid < 256) {
    int j = tid >> 3, ii = tid & 7;
    ((u32*)Vt)[j * 66 + 56 + ii] = 0;
  }

  // ---- P1: [Q|K|V] = x @ W^T, 3-term hi/lo MFMA; x + W frags direct from global
  if (w < 6) {
    const int mi = w >> 1, half = w & 1;
    const int j = 16 * half + l15;
    const float* Wp = (mi == 0) ? Wq : (mi == 1) ? Wk : Wv;
    float bias = (mi == 0) ? bq[j] : (mi == 1) ? bk[j] : bv[j];
    s16x8 bhf[2], blf[2];
#pragma unroll
    for (int kt = 0; kt < 2; ++kt)
      hilo8(Wp + j * 64 + kt * 32 + g * 8, true, bhf[kt], blf[kt]);
    const float* xb = x + (size_t)b * 6400;
#pragma unroll
    for (int tm = 0; tm < 7; ++tm) {
      const int arow = 16 * tm + l15;
      f32x4 acc = zero4;
#pragma unroll
      for (int kt = 0; kt < 2; ++kt) {
        s16x8 ah, al;
        hilo8(xb + arow * 64 + kt * 32 + g * 8, arow < 100, ah, al);
        acc = mfma16(al, bhf[kt], acc);
        acc = mfma16(ah, blf[kt], acc);
        acc = mfma16(ah, bhf[kt], acc);
      }
      const int row0 = 16 * tm + 4 * g;
#pragma unroll
      for (int r = 0; r < 4; ++r) {
        int row = row0 + r;
        float v = acc[r] + bias;
        if (mi == 0)      Qs[row * 36 + j] = f2b(v);
        else if (mi == 1) Ks[row * 36 + j] = f2b(v);
        else              Vt[j * 132 + row] = f2b(v);   // transposed; rows>=100 = bias (A=0 there)
      }
    }
  }
  __syncthreads();

  // ---- P2: S = Q K^T (MFMA), softmax -> A single-bf16 [112][132]
  if (w < 7) {
    const int tm = w;
    s16x8 aq = *(const s16x8*)&Qs[(16 * tm + l15) * 36 + g * 8];
    f32x4 sc[7];
#pragma unroll
    for (int tn = 0; tn < 7; ++tn) {
      s16x8 bb = *(const s16x8*)&Ks[(16 * tn + l15) * 36 + g * 8];
      sc[tn] = mfma16(aq, bb, zero4);
    }
    const int row0 = 16 * tm + 4 * g;
#pragma unroll
    for (int r = 0; r < 4; ++r) {
      const int row = row0 + r;
      float v[7];
#pragma unroll
      for (int tn = 0; tn < 7; ++tn) v[tn] = sc[tn][r];
      if (l15 >= 4) v[6] = -3.0e38f;               // mask cols >= 100
      float m = v[0];
#pragma unroll
      for (int tn = 1; tn < 7; ++tn) m = fmaxf(m, v[tn]);
#pragma unroll
      for (int off = 1; off < 16; off <<= 1) m = fmaxf(m, __shfl_xor(m, off, 16));
      float e[7], s = 0.f;
#pragma unroll
      for (int tn = 0; tn < 7; ++tn) { e[tn] = __expf((v[tn] - m) * 0.03125f); s += e[tn]; }
#pragma unroll
      for (int off = 1; off < 16; off <<= 1) s += __shfl_xor(s, off, 16);
      float rr = __builtin_amdgcn_rcpf(s);
      bool ok = row < 100;
#pragma unroll
      for (int tn = 0; tn < 7; ++tn) {
        float a = ok ? e[tn] * rr : 0.f;
        A16[row * 132 + 16 * tn + l15] = f2b(a);
      }
      if (l15 < 8) ((u32*)A16)[row * 66 + 56 + l15] = 0;   // cols 112..127 := 0
    }
  }
  __syncthreads();

  // ---- P3: feat = A @ V (MFMA, K=128); row-normalize -> chat hi/lo (overlay Q/K)
  if (w < 7) {
    const int tm = w;
    f32x4 f0 = zero4, f1 = zero4;
#pragma unroll
    for (int kt = 0; kt < 4; ++kt) {
      s16x8 a   = *(const s16x8*)&A16[(16 * tm + l15) * 132 + kt * 32 + g * 8];
      s16x8 b0  = *(const s16x8*)&Vt[l15 * 132 + kt * 32 + g * 8];
      s16x8 b1v = *(const s16x8*)&Vt[(16 + l15) * 132 + kt * 32 + g * 8];
      f0 = mfma16(a, b0, f0);
      f1 = mfma16(a, b1v, f1);
    }
    const int row0 = 16 * tm + 4 * g;
#pragma unroll
    for (int r = 0; r < 4; ++r) {
      float v0 = f0[r], v1 = f1[r];
      float s = v0 + v1;
#pragma unroll
      for (int off = 1; off < 16; off <<= 1) s += __shfl_xor(s, off, 16);
      float mean = s * 0.03125f;
      float xc0 = v0 - mean, xc1 = v1 - mean;
      float q = xc0 * xc0 + xc1 * xc1;
#pragma unroll
      for (int off = 1; off < 16; off <<= 1) q += __shfl_xor(q, off, 16);
      float inv = rsqrtf(q + 1e-30f);              // zero rows stay exactly 0
      const int row = row0 + r;
      float c0 = xc0 * inv, c1 = xc1 * inv;
      u16 h0 = f2b(c0), h1 = f2b(c1);
      chh[row * 36 + l15]      = h0;
      chh[row * 36 + 16 + l15] = h1;
      chl[row * 36 + l15]      = f2b(c0 - b2f(h0));
      chl[row * 36 + 16 + l15] = f2b(c1 - b2f(h1));
    }
  }
  __syncthreads();

  // ---- P4: corr = clip(3-term chat@chat^T) -> HBM bf16 (from regs, no LDS)
  if (w < 7) {
    u16* cgu = (u16*)(corr_g + (size_t)b * 10000);
    const int tm = w;
    s16x8 ah = *(const s16x8*)&chh[(16 * tm + l15) * 36 + g * 8];
    s16x8 al = *(const s16x8*)&chl[(16 * tm + l15) * 36 + g * 8];
    const int row0 = 16 * tm + 4 * g;
#pragma unroll
    for (int tn = 0; tn < 7; ++tn) {
      s16x8 bh = *(const s16x8*)&chh[(16 * tn + l15) * 36 + g * 8];
      s16x8 bl = *(const s16x8*)&chl[(16 * tn + l15) * 36 + g * 8];
      f32x4 c = mfma16(al, bh, zero4);
      c = mfma16(ah, bl, c);
      c = mfma16(ah, bh, c);
      const int col = 16 * tn + l15;
      if (col < 100) {
#pragma unroll
        for (int r = 0; r < 4; ++r) {
          const int row = row0 + r;
          if (row < 100)
            cgu[row * 100 + col] = f2b(fminf(1.f, fmaxf(-1.f, c[r])));
        }
      }
    }
  }
}

// ---------------- KB0: t0 = x @ W1^T (f32); z1 = corr @ t0 + b1 ; stats ----------------
// LDS: clLu [100][50] u32 (20000) + tL f32[100][33] (13200) + pad => 4 blocks/CU
__global__ __launch_bounds__(256, 4) void kb0_kernel(
    const float* __restrict__ x,
    const __hip_bfloat16* __restrict__ corr_g,
    const float* __restrict__ W1, const float* __restrict__ b1,
    float* __restrict__ stats_out,
    float* __restrict__ zout)                      // z1 [B,100,32]
{
  __shared__ u32 clLu[100 * 50];
  __shared__ float tL[100 * 33];

  const int b = blockIdx.x, tid = threadIdx.x;

  {
    const u32* cgu = (const u32*)(corr_g + (size_t)b * 10000);
    for (int i = tid; i < 5000; i += 256) {
      int n = (i * 5243) >> 18;                    // i/50 for i<5000
      int mm = i - n * 50;
      clLu[n * 50 + mm] = cgu[i];
    }
  }

  const int j  = tid & 31;                         // FOUT=32
  const int nb = tid >> 5;                         // RP=8, NR=13

  // t0 = x @ W1^T (f32 exact); x rows direct from global (L1-shared across j)
  {
    float wreg[64];
#pragma unroll
    for (int c = 0; c < 64; ++c) wreg[c] = W1[j * 64 + c];
    const float* xb = x + (size_t)b * 6400;
#pragma unroll
    for (int k = 0; k < 13; ++k) {
      int n = nb + k * 8;
      if (n < 100) {
        const float4* xr = (const float4*)(xb + n * 64);
        float a = 0.f;
#pragma unroll
        for (int c4 = 0; c4 < 16; ++c4) {
          float4 xv = xr[c4];
          a = fmaf(xv.x, wreg[c4 * 4 + 0], a);
          a = fmaf(xv.y, wreg[c4 * 4 + 1], a);
          a = fmaf(xv.z, wreg[c4 * 4 + 2], a);
          a = fmaf(xv.w, wreg[c4 * 4 + 3], a);
        }
        tL[n * 33 + j] = a;
      }
    }
  }
  __syncthreads();

  // z1 = corr @ t0 + b1 ; stats
  {
    float acc[13];
    float bj = b1[j];
#pragma unroll
    for (int k = 0; k < 13; ++k) acc[k] = bj;
    int nrow[13];
#pragma unroll
    for (int k = 0; k < 13; ++k) nrow[k] = min(nb + k * 8, 99);
#pragma unroll 5
    for (int m4 = 0; m4 < 25; ++m4) {
      float ta = tL[(m4 * 4 + 0) * 33 + j];
      float tb = tL[(m4 * 4 + 1) * 33 + j];
      float tc = tL[(m4 * 4 + 2) * 33 + j];
      float td = tL[(m4 * 4 + 3) * 33 + j];
#pragma unroll
      for (int k = 0; k < 13; ++k) {
        u32 p0 = clLu[nrow[k] * 50 + 2 * m4];
        u32 p1 = clLu[nrow[k] * 50 + 2 * m4 + 1];
        acc[k] = fmaf(blo(p0), ta, fmaf(bhi(p0), tb,
                 fmaf(blo(p1), tc, fmaf(bhi(p1), td, acc[k]))));
      }
    }
    float* zo = zout + (size_t)b * 3200;
#pragma unroll
    for (int k = 0; k < 13; ++k) {
      int n = nb + k * 8;
      if (n < 100) {
        float v = acc[k];
        zo[n * 32 + j] = v;
        float s = v, ss = v * v;
#pragma unroll
        for (int off = 16; off; off >>= 1) {
          s  += __shfl_xor(s, off, 32);
          ss += __shfl_xor(ss, off, 32);
        }
        if (j == 0) {
          atomicAdd(&stats_out[n], s);
          atomicAdd(&stats_out[100 + n], ss);
        }
      }
    }
  }
}

// ---------------- KB: GCN step; corr bf16-in-LDS [100][50] -> 40.8KB, 4 blocks/CU ----------------
template<int FIN, int FOUT>
__global__ __launch_bounds__(256, 4) void kb_kernel(
    const float* __restrict__ zin,
    const __hip_bfloat16* __restrict__ corr_g,
    const float* __restrict__ W, const float* __restrict__ bias,
    const float* __restrict__ stats_in, float* __restrict__ stats_out,
    float* __restrict__ zout)
{
  constexpr int LOGF  = (FOUT == 16) ? 4 : (FOUT == 8) ? 3 : (FOUT == 4) ? 2 : 1;
  constexpr int LOGFI = (FIN == 32) ? 5 : (FIN == 16) ? 4 : (FIN == 8) ? 3 : 2;
  constexpr int RP = 256 / FOUT;
  constexpr int NR = (100 + RP - 1) / RP;

  __shared__ u32 clLu[100 * 50];
  __shared__ float mS[100], vS[100];
  __shared__ float hL[100 * 33];
  __shared__ float tL[100 * (FOUT + 1)];

  const int b = blockIdx.x, tid = threadIdx.x;

  {
    const u32* cgu = (const u32*)(corr_g + (size_t)b * 10000);
    for (int i = tid; i < 5000; i += 256) {
      int n = (i * 5243) >> 18;
      int mm = i - n * 50;
      clLu[n * 50 + mm] = cgu[i];
    }
  }
  if (tid < 100) {
    float cnt  = 8192.0f * (float)FIN;
    float mean = stats_in[tid] / cnt;
    float var  = stats_in[100 + tid] / cnt - mean * mean;
    mS[tid] = mean;
    vS[tid] = rsqrtf(var + 1e-5f);
  }
  __syncthreads();

  {
    const float4* zb4 = (const float4*)(zin + (size_t)b * 100 * FIN);
    for (int i4 = tid; i4 < 25 * FIN; i4 += 256) {
      int n = i4 >> (LOGFI - 2);
      int c = (i4 << 2) & (FIN - 1);
      float4 z = zb4[i4];
      float mn = mS[n], iv = vS[n];
      hL[n * 33 + c + 0] = fast_tanh((z.x - mn) * iv);
      hL[n * 33 + c + 1] = fast_tanh((z.y - mn) * iv);
      hL[n * 33 + c + 2] = fast_tanh((z.z - mn) * iv);
      hL[n * 33 + c + 3] = fast_tanh((z.w - mn) * iv);
    }
  }
  __syncthreads();

  const int j  = tid & (FOUT - 1);
  const int nb = tid >> LOGF;

  {
    float wreg[FIN];
#pragma unroll
    for (int c = 0; c < FIN; ++c) wreg[c] = W[j * FIN + c];
#pragma unroll
    for (int k = 0; k < NR; ++k) {
      int n = nb + k * RP;
      if (n < 100) {
        float a = 0.f;
#pragma unroll
        for (int c = 0; c < FIN; ++c) a = fmaf(hL[n * 33 + c], wreg[c], a);
        tL[n * (FOUT + 1) + j] = a;
      }
    }
  }
  __syncthreads();

  {
    float acc[NR];
    float bj = bias[j];
#pragma unroll
    for (int k = 0; k < NR; ++k) acc[k] = bj;
    int nrow[NR];
#pragma unroll
    for (int k = 0; k < NR; ++k) nrow[k] = min(nb + k * RP, 99);
#pragma unroll 5
    for (int m4 = 0; m4 < 25; ++m4) {
      float ta = tL[(m4 * 4 + 0) * (FOUT + 1) + j];
      float tb = tL[(m4 * 4 + 1) * (FOUT + 1) + j];
      float tc = tL[(m4 * 4 + 2) * (FOUT + 1) + j];
      float td = tL[(m4 * 4 + 3) * (FOUT + 1) + j];
#pragma unroll
      for (int k = 0; k < NR; ++k) {
        u32 p0 = clLu[nrow[k] * 50 + 2 * m4];
        u32 p1 = clLu[nrow[k] * 50 + 2 * m4 + 1];
        acc[k] = fmaf(blo(p0), ta, fmaf(bhi(p0), tb,
                 fmaf(blo(p1), tc, fmaf(bhi(p1), td, acc[k]))));
      }
    }
    float* zo = zout + (size_t)b * 100 * FOUT;
#pragma unroll
    for (int k = 0; k < NR; ++k) {
      int n = nb + k * RP;
      if (n < 100) {
        float v = acc[k];
        zo[n * FOUT + j] = v;
        float s = v, ss = v * v;
#pragma unroll
        for (int off = FOUT >> 1; off; off >>= 1) {
          s  += __shfl_xor(s, off, FOUT);
          ss += __shfl_xor(ss, off, FOUT);
        }
        if (j == 0) {
          atomicAdd(&stats_out[n], s);
          atomicAdd(&stats_out[100 + n], ss);
        }
      }
    }
  }
}

// ---------------- KF: final BN+tanh + [200]->[2] head ----------------
__global__ __launch_bounds__(256) void kf_kernel(
    const float* __restrict__ z5, const float* __restrict__ stats5,
    const float* __restrict__ Wf, const float* __restrict__ bfv,
    float* __restrict__ out)
{
  __shared__ float mS[100], vS[100];
  const int tid = threadIdx.x;
  if (tid < 100) {
    float cnt  = 8192.0f * 2.0f;
    float mean = stats5[tid] / cnt;
    float var  = stats5[100 + tid] / cnt - mean * mean;
    mS[tid] = mean;
    vS[tid] = rsqrtf(var + 1e-5f);
  }
  __syncthreads();
  const int wvid = tid >> 6, lane = tid & 63;
  const int b = blockIdx.x * 4 + wvid;
  const float* zb = z5 + (size_t)b * 200;
  float a0 = 0.f, a1 = 0.f;
#pragma unroll
  for (int p = 0; p < 4; ++p) {
    int jj = lane + p * 64;
    if (jj < 200) {
      int n = jj >> 1;
      float hv = fast_tanh((zb[jj] - mS[n]) * vS[n]);
      a0 = fmaf(hv, Wf[jj], a0);
      a1 = fmaf(hv, Wf[200 + jj], a1);
    }
  }
#pragma unroll
  for (int off = 32; off; off >>= 1) {
    a0 += __shfl_xor(a0, off, 64);
    a1 += __shfl_xor(a1, off, 64);
  }
  if (lane == 0) {
    out[b * 2 + 0] = a0 + bfv[0];
    out[b * 2 + 1] = a1 + bfv[1];
  }
}

extern "C" void kernel_launch(void* const* d_in, const int* in_sizes, int n_in,
                              void* d_out, int out_size, void* d_ws, size_t ws_size,
                              hipStream_t stream)
{
  const float* x  = (const float*)d_in[0];
  const float* Wq = (const float*)d_in[1];
  const float* bq = (const float*)d_in[2];
  const float* Wk = (const float*)d_in[3];
  const float* bk = (const float*)d_in[4];
  const float* Wv = (const float*)d_in[5];
  const float* bv = (const float*)d_in[6];
  const float* W1 = (const float*)d_in[7];
  const float* b1 = (const float*)d_in[8];
  const float* W2 = (const float*)d_in[9];
  const float* b2 = (const float*)d_in[10];
  const float* W3 = (const float*)d_in[11];
  const float* b3 = (const float*)d_in[12];
  const float* W4 = (const float*)d_in[13];
  const float* b4 = (const float*)d_in[14];
  const float* W5 = (const float*)d_in[15];
  const float* b5 = (const float*)d_in[16];
  const float* Wf = (const float*)d_in[17];
  const float* bf = (const float*)d_in[18];
  float* out = (float*)d_out;

  char* ws = (char*)d_ws;
  // ws: corr bf16 [8192,100,100] @0 ; zA f32 [8192,100,32] @163840000 ;
  //     zB f32 [8192,100,16] @268697600 ; stats 5*[200] f32 @321126400
  const size_t NEED = 321130400ull;
  if (ws_size < NEED) return;

  __hip_bfloat16* corr_g = (__hip_bfloat16*)ws;
  float* zA    = (float*)(ws + 163840000ull);
  float* zB    = (float*)(ws + 268697600ull);
  float* stats = (float*)(ws + 321126400ull);

  (void)hipMemsetAsync(stats, 0, 5 * 200 * sizeof(float), stream);

  ka_kernel<<<8192, 512, 0, stream>>>(x, Wq, bq, Wk, bk, Wv, bv, corr_g);
  kb0_kernel<<<8192, 256, 0, stream>>>(x, corr_g, W1, b1, stats, zA);
  kb_kernel<32, 16><<<8192, 256, 0, stream>>>(zA, corr_g, W2, b2, stats,       stats + 200, zB);
  kb_kernel<16,  8><<<8192, 256, 0, stream>>>(zB, corr_g, W3, b3, stats + 200, stats + 400, zA);
  kb_kernel< 8,  4><<<8192, 256, 0, stream>>>(zA, corr_g, W4, b4, stats + 400, stats + 600, zB);
  kb_kernel< 4,  2><<<8192, 256, 0, stream>>>(zB, corr_g, W5, b5, stats + 600, stats + 800, zA);
  kf_kernel<<<2048, 256, 0, stream>>>(zA, stats + 800, Wf, bf, out);
}

// Round 13
// 4265.482 us; speedup vs baseline: 1.0112x; 1.0112x over previous
//
#include <hip/hip_runtime.h>
#include <hip/hip_bf16.h>

// whole_network: attention -> corrcoef -> 5x (GCN + BatchNorm(node) + tanh) -> linear head
// B=8192, N=100 (pad 112), T=64.
// R13: kb0's t0 phase rewritten as hi/lo MFMA (x,W1 frags from global) -- removes the
// wreg[64] scratch spill (R12: WRITE_SIZE 447MB vs 105MB expected). All else = R12.

typedef unsigned int u32;
typedef unsigned short u16;
typedef float f32x4 __attribute__((ext_vector_type(4)));
typedef short s16x8 __attribute__((ext_vector_type(8)));

__device__ __forceinline__ f32x4 mfma16(s16x8 a, s16x8 b, f32x4 c) {
  return __builtin_amdgcn_mfma_f32_16x16x32_bf16(a, b, c, 0, 0, 0);
}
__device__ __forceinline__ u16 f2b(float f) {
  __hip_bfloat16 h = __float2bfloat16(f);
  u16 u; __builtin_memcpy(&u, &h, 2); return u;
}
__device__ __forceinline__ float b2f(u16 u) { return __uint_as_float((u32)u << 16); }
__device__ __forceinline__ float blo(u32 u) { return __uint_as_float(u << 16); }
__device__ __forceinline__ float bhi(u32 u) { return __uint_as_float(u & 0xffff0000u); }
__device__ __forceinline__ float fast_tanh(float x) {
  float e = __expf(2.0f * x);
  return 1.0f - 2.0f * __builtin_amdgcn_rcpf(e + 1.0f);
}
// build hi/lo bf16 fragments from 8 f32 (global), zero if !ok
__device__ __forceinline__ void hilo8(const float* p, bool ok, s16x8& hi, s16x8& lo) {
  const float4* p4 = (const float4*)p;
  float4 a = {0.f,0.f,0.f,0.f}, b = {0.f,0.f,0.f,0.f};
  if (ok) { a = p4[0]; b = p4[1]; }
  float v[8] = {a.x,a.y,a.z,a.w,b.x,b.y,b.z,b.w};
#pragma unroll
  for (int e = 0; e < 8; ++e) {
    u16 hh = f2b(v[e]);
    hi[e] = (short)hh;
    lo[e] = (short)f2b(v[e] - b2f(hh));
  }
}

// ---------------- KA LDS map (BYTE offsets), total 54144 => 3 blocks/CU ----------------
#define KA_QS_B   0
#define KA_KS_B   8064
#define KA_CHH_B  0
#define KA_CHL_B  8064
#define KA_A_B    16128
#define KA_VT_B   45696
#define KA_SMEM_B 54144

__global__ __launch_bounds__(512, 6) void ka_kernel(
    const float* __restrict__ x,
    const float* __restrict__ Wq, const float* __restrict__ bq,
    const float* __restrict__ Wk, const float* __restrict__ bk,
    const float* __restrict__ Wv, const float* __restrict__ bv,
    __hip_bfloat16* __restrict__ corr_g)   // [B,100,100] bf16
{
  __shared__ __align__(16) char smem[KA_SMEM_B];
  u16* Qs  = (u16*)(smem + KA_QS_B);
  u16* Ks  = (u16*)(smem + KA_KS_B);
  u16* chh = (u16*)(smem + KA_CHH_B);
  u16* chl = (u16*)(smem + KA_CHL_B);
  u16* A16 = (u16*)(smem + KA_A_B);
  u16* Vt  = (u16*)(smem + KA_VT_B);

  const int b = blockIdx.x, tid = threadIdx.x;
  const int w = tid >> 6, l15 = tid & 15, g = (tid & 63) >> 4;
  const f32x4 zero4 = {0.f, 0.f, 0.f, 0.f};

  if (tid < 256) {
    int j = tid >> 3, ii = tid & 7;
    ((u32*)Vt)[j * 66 + 56 + ii] = 0;
  }

  // ---- P1: [Q|K|V] = x @ W^T, 3-term hi/lo MFMA; x + W frags direct from global
  if (w < 6) {
    const int mi = w >> 1, half = w & 1;
    const int j = 16 * half + l15;
    const float* Wp = (mi == 0) ? Wq : (mi == 1) ? Wk : Wv;
    float bias = (mi == 0) ? bq[j] : (mi == 1) ? bk[j] : bv[j];
    s16x8 bhf[2], blf[2];
#pragma unroll
    for (int kt = 0; kt < 2; ++kt)
      hilo8(Wp + j * 64 + kt * 32 + g * 8, true, bhf[kt], blf[kt]);
    const float* xb = x + (size_t)b * 6400;
#pragma unroll
    for (int tm = 0; tm < 7; ++tm) {
      const int arow = 16 * tm + l15;
      f32x4 acc = zero4;
#pragma unroll
      for (int kt = 0; kt < 2; ++kt) {
        s16x8 ah, al;
        hilo8(xb + arow * 64 + kt * 32 + g * 8, arow < 100, ah, al);
        acc = mfma16(al, bhf[kt], acc);
        acc = mfma16(ah, blf[kt], acc);
        acc = mfma16(ah, bhf[kt], acc);
      }
      const int row0 = 16 * tm + 4 * g;
#pragma unroll
      for (int r = 0; r < 4; ++r) {
        int row = row0 + r;
        float v = acc[r] + bias;
        if (mi == 0)      Qs[row * 36 + j] = f2b(v);
        else if (mi == 1) Ks[row * 36 + j] = f2b(v);
        else              Vt[j * 132 + row] = f2b(v);   // transposed; rows>=100 = bias (A=0 there)
      }
    }
  }
  __syncthreads();

  // ---- P2: S = Q K^T (MFMA), softmax -> A single-bf16 [112][132]
  if (w < 7) {
    const int tm = w;
    s16x8 aq = *(const s16x8*)&Qs[(16 * tm + l15) * 36 + g * 8];
    f32x4 sc[7];
#pragma unroll
    for (int tn = 0; tn < 7; ++tn) {
      s16x8 bb = *(const s16x8*)&Ks[(16 * tn + l15) * 36 + g * 8];
      sc[tn] = mfma16(aq, bb, zero4);
    }
    const int row0 = 16 * tm + 4 * g;
#pragma unroll
    for (int r = 0; r < 4; ++r) {
      const int row = row0 + r;
      float v[7];
#pragma unroll
      for (int tn = 0; tn < 7; ++tn) v[tn] = sc[tn][r];
      if (l15 >= 4) v[6] = -3.0e38f;               // mask cols >= 100
      float m = v[0];
#pragma unroll
      for (int tn = 1; tn < 7; ++tn) m = fmaxf(m, v[tn]);
#pragma unroll
      for (int off = 1; off < 16; off <<= 1) m = fmaxf(m, __shfl_xor(m, off, 16));
      float e[7], s = 0.f;
#pragma unroll
      for (int tn = 0; tn < 7; ++tn) { e[tn] = __expf((v[tn] - m) * 0.03125f); s += e[tn]; }
#pragma unroll
      for (int off = 1; off < 16; off <<= 1) s += __shfl_xor(s, off, 16);
      float rr = __builtin_amdgcn_rcpf(s);
      bool ok = row < 100;
#pragma unroll
      for (int tn = 0; tn < 7; ++tn) {
        float a = ok ? e[tn] * rr : 0.f;
        A16[row * 132 + 16 * tn + l15] = f2b(a);
      }
      if (l15 < 8) ((u32*)A16)[row * 66 + 56 + l15] = 0;   // cols 112..127 := 0
    }
  }
  __syncthreads();

  // ---- P3: feat = A @ V (MFMA, K=128); row-normalize -> chat hi/lo (overlay Q/K)
  if (w < 7) {
    const int tm = w;
    f32x4 f0 = zero4, f1 = zero4;
#pragma unroll
    for (int kt = 0; kt < 4; ++kt) {
      s16x8 a   = *(const s16x8*)&A16[(16 * tm + l15) * 132 + kt * 32 + g * 8];
      s16x8 b0  = *(const s16x8*)&Vt[l15 * 132 + kt * 32 + g * 8];
      s16x8 b1v = *(const s16x8*)&Vt[(16 + l15) * 132 + kt * 32 + g * 8];
      f0 = mfma16(a, b0, f0);
      f1 = mfma16(a, b1v, f1);
    }
    const int row0 = 16 * tm + 4 * g;
#pragma unroll
    for (int r = 0; r < 4; ++r) {
      float v0 = f0[r], v1 = f1[r];
      float s = v0 + v1;
#pragma unroll
      for (int off = 1; off < 16; off <<= 1) s += __shfl_xor(s, off, 16);
      float mean = s * 0.03125f;
      float xc0 = v0 - mean, xc1 = v1 - mean;
      float q = xc0 * xc0 + xc1 * xc1;
#pragma unroll
      for (int off = 1; off < 16; off <<= 1) q += __shfl_xor(q, off, 16);
      float inv = rsqrtf(q + 1e-30f);              // zero rows stay exactly 0
      const int row = row0 + r;
      float c0 = xc0 * inv, c1 = xc1 * inv;
      u16 h0 = f2b(c0), h1 = f2b(c1);
      chh[row * 36 + l15]      = h0;
      chh[row * 36 + 16 + l15] = h1;
      chl[row * 36 + l15]      = f2b(c0 - b2f(h0));
      chl[row * 36 + 16 + l15] = f2b(c1 - b2f(h1));
    }
  }
  __syncthreads();

  // ---- P4: corr = clip(3-term chat@chat^T) -> HBM bf16 (from regs, no LDS)
  if (w < 7) {
    u16* cgu = (u16*)(corr_g + (size_t)b * 10000);
    const int tm = w;
    s16x8 ah = *(const s16x8*)&chh[(16 * tm + l15) * 36 + g * 8];
    s16x8 al = *(const s16x8*)&chl[(16 * tm + l15) * 36 + g * 8];
    const int row0 = 16 * tm + 4 * g;
#pragma unroll
    for (int tn = 0; tn < 7; ++tn) {
      s16x8 bh = *(const s16x8*)&chh[(16 * tn + l15) * 36 + g * 8];
      s16x8 bl = *(const s16x8*)&chl[(16 * tn + l15) * 36 + g * 8];
      f32x4 c = mfma16(al, bh, zero4);
      c = mfma16(ah, bl, c);
      c = mfma16(ah, bh, c);
      const int col = 16 * tn + l15;
      if (col < 100) {
#pragma unroll
        for (int r = 0; r < 4; ++r) {
          const int row = row0 + r;
          if (row < 100)
            cgu[row * 100 + col] = f2b(fminf(1.f, fmaxf(-1.f, c[r])));
        }
      }
    }
  }
}

// ---------------- KB0: t0 = x @ W1^T (hi/lo MFMA, ~exact); z1 = corr @ t0 + b1 ; stats ----
// LDS: clLu [100][50] u32 (20000) + tL f32[100][33] (13200) => 4 blocks/CU. No wreg spill.
__global__ __launch_bounds__(256, 4) void kb0_kernel(
    const float* __restrict__ x,
    const __hip_bfloat16* __restrict__ corr_g,
    const float* __restrict__ W1, const float* __restrict__ b1,
    float* __restrict__ stats_out,
    float* __restrict__ zout)                      // z1 [B,100,32]
{
  __shared__ u32 clLu[100 * 50];
  __shared__ float tL[100 * 33];

  const int b = blockIdx.x, tid = threadIdx.x;
  const int w = tid >> 6, l15 = tid & 15, g = (tid & 63) >> 4;
  const f32x4 zero4 = {0.f, 0.f, 0.f, 0.f};

  // corr stage (all threads) -- VMEM overlaps the MFMA below (same phase)
  {
    const u32* cgu = (const u32*)(corr_g + (size_t)b * 10000);
    for (int i = tid; i < 5000; i += 256) {
      int n = (i * 5243) >> 18;                    // i/50 for i<5000
      int mm = i - n * 50;
      clLu[n * 50 + mm] = cgu[i];
    }
  }

  // t0 = x @ W1^T via 3-term hi/lo MFMA; frags from global (VGPR-light, no spill)
  {
    s16x8 bhf[2][2], blf[2][2];                    // [j-half][kt]
#pragma unroll
    for (int half = 0; half < 2; ++half) {
      const int j = 16 * half + l15;
#pragma unroll
      for (int kt = 0; kt < 2; ++kt)
        hilo8(W1 + j * 64 + kt * 32 + g * 8, true, bhf[half][kt], blf[half][kt]);
    }
    const float* xb = x + (size_t)b * 6400;
#pragma unroll
    for (int t2 = 0; t2 < 2; ++t2) {
      const int tm = w + 4 * t2;
      if (tm < 7) {
        const int arow = 16 * tm + l15;
        s16x8 ah[2], al[2];
#pragma unroll
        for (int kt = 0; kt < 2; ++kt)
          hilo8(xb + arow * 64 + kt * 32 + g * 8, arow < 100, ah[kt], al[kt]);
        const int row0 = 16 * tm + 4 * g;
#pragma unroll
        for (int half = 0; half < 2; ++half) {
          f32x4 acc = zero4;
#pragma unroll
          for (int kt = 0; kt < 2; ++kt) {
            acc = mfma16(al[kt], bhf[half][kt], acc);
            acc = mfma16(ah[kt], blf[half][kt], acc);
            acc = mfma16(ah[kt], bhf[half][kt], acc);
          }
          const int j = 16 * half + l15;
#pragma unroll
          for (int r = 0; r < 4; ++r) {
            int row = row0 + r;
            if (row < 100) tL[row * 33 + j] = acc[r];
          }
        }
      }
    }
  }
  __syncthreads();

  // z1 = corr @ t0 + b1 ; stats (proven VALU form)
  {
    const int j  = tid & 31;
    const int nb = tid >> 5;
    float acc[13];
    float bj = b1[j];
#pragma unroll
    for (int k = 0; k < 13; ++k) acc[k] = bj;
    int nrow[13];
#pragma unroll
    for (int k = 0; k < 13; ++k) nrow[k] = min(nb + k * 8, 99);
#pragma unroll 5
    for (int m4 = 0; m4 < 25; ++m4) {
      float ta = tL[(m4 * 4 + 0) * 33 + j];
      float tb = tL[(m4 * 4 + 1) * 33 + j];
      float tc = tL[(m4 * 4 + 2) * 33 + j];
      float td = tL[(m4 * 4 + 3) * 33 + j];
#pragma unroll
      for (int k = 0; k < 13; ++k) {
        u32 p0 = clLu[nrow[k] * 50 + 2 * m4];
        u32 p1 = clLu[nrow[k] * 50 + 2 * m4 + 1];
        acc[k] = fmaf(blo(p0), ta, fmaf(bhi(p0), tb,
                 fmaf(blo(p1), tc, fmaf(bhi(p1), td, acc[k]))));
      }
    }
    float* zo = zout + (size_t)b * 3200;
#pragma unroll
    for (int k = 0; k < 13; ++k) {
      int n = nb + k * 8;
      if (n < 100) {
        float v = acc[k];
        zo[n * 32 + j] = v;
        float s = v, ss = v * v;
#pragma unroll
        for (int off = 16; off; off >>= 1) {
          s  += __shfl_xor(s, off, 32);
          ss += __shfl_xor(ss, off, 32);
        }
        if (j == 0) {
          atomicAdd(&stats_out[n], s);
          atomicAdd(&stats_out[100 + n], ss);
        }
      }
    }
  }
}

// ---------------- KB: GCN step; corr bf16-in-LDS [100][50] -> 40.8KB, 4 blocks/CU ----------------
template<int FIN, int FOUT>
__global__ __launch_bounds__(256, 4) void kb_kernel(
    const float* __restrict__ zin,
    const __hip_bfloat16* __restrict__ corr_g,
    const float* __restrict__ W, const float* __restrict__ bias,
    const float* __restrict__ stats_in, float* __restrict__ stats_out,
    float* __restrict__ zout)
{
  constexpr int LOGF  = (FOUT == 16) ? 4 : (FOUT == 8) ? 3 : (FOUT == 4) ? 2 : 1;
  constexpr int LOGFI = (FIN == 32) ? 5 : (FIN == 16) ? 4 : (FIN == 8) ? 3 : 2;
  constexpr int RP = 256 / FOUT;
  constexpr int NR = (100 + RP - 1) / RP;

  __shared__ u32 clLu[100 * 50];
  __shared__ float mS[100], vS[100];
  __shared__ float hL[100 * 33];
  __shared__ float tL[100 * (FOUT + 1)];

  const int b = blockIdx.x, tid = threadIdx.x;

  {
    const u32* cgu = (const u32*)(corr_g + (size_t)b * 10000);
    for (int i = tid; i < 5000; i += 256) {
      int n = (i * 5243) >> 18;
      int mm = i - n * 50;
      clLu[n * 50 + mm] = cgu[i];
    }
  }
  if (tid < 100) {
    float cnt  = 8192.0f * (float)FIN;
    float mean = stats_in[tid] / cnt;
    float var  = stats_in[100 + tid] / cnt - mean * mean;
    mS[tid] = mean;
    vS[tid] = rsqrtf(var + 1e-5f);
  }
  __syncthreads();

  {
    const float4* zb4 = (const float4*)(zin + (size_t)b * 100 * FIN);
    for (int i4 = tid; i4 < 25 * FIN; i4 += 256) {
      int n = i4 >> (LOGFI - 2);
      int c = (i4 << 2) & (FIN - 1);
      float4 z = zb4[i4];
      float mn = mS[n], iv = vS[n];
      hL[n * 33 + c + 0] = fast_tanh((z.x - mn) * iv);
      hL[n * 33 + c + 1] = fast_tanh((z.y - mn) * iv);
      hL[n * 33 + c + 2] = fast_tanh((z.z - mn) * iv);
      hL[n * 33 + c + 3] = fast_tanh((z.w - mn) * iv);
    }
  }
  __syncthreads();

  const int j  = tid & (FOUT - 1);
  const int nb = tid >> LOGF;

  {
    float wreg[FIN];
#pragma unroll
    for (int c = 0; c < FIN; ++c) wreg[c] = W[j * FIN + c];
#pragma unroll
    for (int k = 0; k < NR; ++k) {
      int n = nb + k * RP;
      if (n < 100) {
        float a = 0.f;
#pragma unroll
        for (int c = 0; c < FIN; ++c) a = fmaf(hL[n * 33 + c], wreg[c], a);
        tL[n * (FOUT + 1) + j] = a;
      }
    }
  }
  __syncthreads();

  {
    float acc[NR];
    float bj = bias[j];
#pragma unroll
    for (int k = 0; k < NR; ++k) acc[k] = bj;
    int nrow[NR];
#pragma unroll
    for (int k = 0; k < NR; ++k) nrow[k] = min(nb + k * RP, 99);
#pragma unroll 5
    for (int m4 = 0; m4 < 25; ++m4) {
      float ta = tL[(m4 * 4 + 0) * (FOUT + 1) + j];
      float tb = tL[(m4 * 4 + 1) * (FOUT + 1) + j];
      float tc = tL[(m4 * 4 + 2) * (FOUT + 1) + j];
      float td = tL[(m4 * 4 + 3) * (FOUT + 1) + j];
#pragma unroll
      for (int k = 0; k < NR; ++k) {
        u32 p0 = clLu[nrow[k] * 50 + 2 * m4];
        u32 p1 = clLu[nrow[k] * 50 + 2 * m4 + 1];
        acc[k] = fmaf(blo(p0), ta, fmaf(bhi(p0), tb,
                 fmaf(blo(p1), tc, fmaf(bhi(p1), td, acc[k]))));
      }
    }
    float* zo = zout + (size_t)b * 100 * FOUT;
#pragma unroll
    for (int k = 0; k < NR; ++k) {
      int n = nb + k * RP;
      if (n < 100) {
        float v = acc[k];
        zo[n * FOUT + j] = v;
        float s = v, ss = v * v;
#pragma unroll
        for (int off = FOUT >> 1; off; off >>= 1) {
          s  += __shfl_xor(s, off, FOUT);
          ss += __shfl_xor(ss, off, FOUT);
        }
        if (j == 0) {
          atomicAdd(&stats_out[n], s);
          atomicAdd(&stats_out[100 + n], ss);
        }
      }
    }
  }
}

// ---------------- KF: final BN+tanh + [200]->[2] head ----------------
__global__ __launch_bounds__(256) void kf_kernel(
    const float* __restrict__ z5, const float* __restrict__ stats5,
    const float* __restrict__ Wf, const float* __restrict__ bfv,
    float* __restrict__ out)
{
  __shared__ float mS[100], vS[100];
  const int tid = threadIdx.x;
  if (tid < 100) {
    float cnt  = 8192.0f * 2.0f;
    float mean = stats5[tid] / cnt;
    float var  = stats5[100 + tid] / cnt - mean * mean;
    mS[tid] = mean;
    vS[tid] = rsqrtf(var + 1e-5f);
  }
  __syncthreads();
  const int wvid = tid >> 6, lane = tid & 63;
  const int b = blockIdx.x * 4 + wvid;
  const float* zb = z5 + (size_t)b * 200;
  float a0 = 0.f, a1 = 0.f;
#pragma unroll
  for (int p = 0; p < 4; ++p) {
    int jj = lane + p * 64;
    if (jj < 200) {
      int n = jj >> 1;
      float hv = fast_tanh((zb[jj] - mS[n]) * vS[n]);
      a0 = fmaf(hv, Wf[jj], a0);
      a1 = fmaf(hv, Wf[200 + jj], a1);
    }
  }
#pragma unroll
  for (int off = 32; off; off >>= 1) {
    a0 += __shfl_xor(a0, off, 64);
    a1 += __shfl_xor(a1, off, 64);
  }
  if (lane == 0) {
    out[b * 2 + 0] = a0 + bfv[0];
    out[b * 2 + 1] = a1 + bfv[1];
  }
}

extern "C" void kernel_launch(void* const* d_in, const int* in_sizes, int n_in,
                              void* d_out, int out_size, void* d_ws, size_t ws_size,
                              hipStream_t stream)
{
  const float* x  = (const float*)d_in[0];
  const float* Wq = (const float*)d_in[1];
  const float* bq = (const float*)d_in[2];
  const float* Wk = (const float*)d_in[3];
  const float* bk = (const float*)d_in[4];
  const float* Wv = (const float*)d_in[5];
  const float* bv = (const float*)d_in[6];
  const float* W1 = (const float*)d_in[7];
  const float* b1 = (const float*)d_in[8];
  const float* W2 = (const float*)d_in[9];
  const float* b2 = (const float*)d_in[10];
  const float* W3 = (const float*)d_in[11];
  const float* b3 = (const float*)d_in[12];
  const float* W4 = (const float*)d_in[13];
  const float* b4 = (const float*)d_in[14];
  const float* W5 = (const float*)d_in[15];
  const float* b5 = (const float*)d_in[16];
  const float* Wf = (const float*)d_in[17];
  const float* bf = (const float*)d_in[18];
  float* out = (float*)d_out;

  char* ws = (char*)d_ws;
  // ws: corr bf16 [8192,100,100] @0 ; zA f32 [8192,100,32] @163840000 ;
  //     zB f32 [8192,100,16] @268697600 ; stats 5*[200] f32 @321126400
  const size_t NEED = 321130400ull;
  if (ws_size < NEED) return;

  __hip_bfloat16* corr_g = (__hip_bfloat16*)ws;
  float* zA    = (float*)(ws + 163840000ull);
  float* zB    = (float*)(ws + 268697600ull);
  float* stats = (float*)(ws + 321126400ull);

  (void)hipMemsetAsync(stats, 0, 5 * 200 * sizeof(float), stream);

  ka_kernel<<<8192, 512, 0, stream>>>(x, Wq, bq, Wk, bk, Wv, bv, corr_g);
  kb0_kernel<<<8192, 256, 0, stream>>>(x, corr_g, W1, b1, stats, zA);
  kb_kernel<32, 16><<<8192, 256, 0, stream>>>(zA, corr_g, W2, b2, stats,       stats + 200, zB);
  kb_kernel<16,  8><<<8192, 256, 0, stream>>>(zB, corr_g, W3, b3, stats + 200, stats + 400, zA);
  kb_kernel< 8,  4><<<8192, 256, 0, stream>>>(zA, corr_g, W4, b4, stats + 400, stats + 600, zB);
  kb_kernel< 4,  2><<<8192, 256, 0, stream>>>(zB, corr_g, W5, b5, stats + 600, stats + 800, zA);
  kf_kernel<<<2048, 256, 0, stream>>>(zA, stats + 800, Wf, bf, out);
}

// Round 14
// 4252.292 us; speedup vs baseline: 1.0144x; 1.0031x over previous
//
#include <hip/hip_runtime.h>
#include <hip/hip_bf16.h>

// whole_network: attention -> corrcoef -> 5x (GCN + BatchNorm(node) + tanh) -> linear head
// B=8192, N=100 (pad 112), T=64.
// R14: kb0 restructured to the proven "coalesced global -> LDS -> consume" pattern:
//   P0 x float4 -> LDS [112][68] f32 (rows>=100 zero); P1 t0 MFMA with frags from LDS;
//   P2 corr -> LDS (overlays x); P3 z1 + stats. 43.7KB -> 3 blocks/CU.
// KA/KB/KF byte-identical to R13.

typedef unsigned int u32;
typedef unsigned short u16;
typedef float f32x4 __attribute__((ext_vector_type(4)));
typedef short s16x8 __attribute__((ext_vector_type(8)));

__device__ __forceinline__ f32x4 mfma16(s16x8 a, s16x8 b, f32x4 c) {
  return __builtin_amdgcn_mfma_f32_16x16x32_bf16(a, b, c, 0, 0, 0);
}
__device__ __forceinline__ u16 f2b(float f) {
  __hip_bfloat16 h = __float2bfloat16(f);
  u16 u; __builtin_memcpy(&u, &h, 2); return u;
}
__device__ __forceinline__ float b2f(u16 u) { return __uint_as_float((u32)u << 16); }
__device__ __forceinline__ float blo(u32 u) { return __uint_as_float(u << 16); }
__device__ __forceinline__ float bhi(u32 u) { return __uint_as_float(u & 0xffff0000u); }
__device__ __forceinline__ float fast_tanh(float x) {
  float e = __expf(2.0f * x);
  return 1.0f - 2.0f * __builtin_amdgcn_rcpf(e + 1.0f);
}
// build hi/lo bf16 fragments from 8 f32 at p (global), zero if !ok
__device__ __forceinline__ void hilo8(const float* p, bool ok, s16x8& hi, s16x8& lo) {
  const float4* p4 = (const float4*)p;
  float4 a = {0.f,0.f,0.f,0.f}, b = {0.f,0.f,0.f,0.f};
  if (ok) { a = p4[0]; b = p4[1]; }
  float v[8] = {a.x,a.y,a.z,a.w,b.x,b.y,b.z,b.w};
#pragma unroll
  for (int e = 0; e < 8; ++e) {
    u16 hh = f2b(v[e]);
    hi[e] = (short)hh;
    lo[e] = (short)f2b(v[e] - b2f(hh));
  }
}
// same but from LDS, unconditional (rows pre-zeroed)
__device__ __forceinline__ void hilo8_lds(const float* p, s16x8& hi, s16x8& lo) {
  const f32x4* p4 = (const f32x4*)p;
  f32x4 a = p4[0], b = p4[1];
  float v[8] = {a[0],a[1],a[2],a[3],b[0],b[1],b[2],b[3]};
#pragma unroll
  for (int e = 0; e < 8; ++e) {
    u16 hh = f2b(v[e]);
    hi[e] = (short)hh;
    lo[e] = (short)f2b(v[e] - b2f(hh));
  }
}

// ---------------- KA LDS map (BYTE offsets), total 54144 => 3 blocks/CU ----------------
#define KA_QS_B   0
#define KA_KS_B   8064
#define KA_CHH_B  0
#define KA_CHL_B  8064
#define KA_A_B    16128
#define KA_VT_B   45696
#define KA_SMEM_B 54144

__global__ __launch_bounds__(512, 6) void ka_kernel(
    const float* __restrict__ x,
    const float* __restrict__ Wq, const float* __restrict__ bq,
    const float* __restrict__ Wk, const float* __restrict__ bk,
    const float* __restrict__ Wv, const float* __restrict__ bv,
    __hip_bfloat16* __restrict__ corr_g)   // [B,100,100] bf16
{
  __shared__ __align__(16) char smem[KA_SMEM_B];
  u16* Qs  = (u16*)(smem + KA_QS_B);
  u16* Ks  = (u16*)(smem + KA_KS_B);
  u16* chh = (u16*)(smem + KA_CHH_B);
  u16* chl = (u16*)(smem + KA_CHL_B);
  u16* A16 = (u16*)(smem + KA_A_B);
  u16* Vt  = (u16*)(smem + KA_VT_B);

  const int b = blockIdx.x, tid = threadIdx.x;
  const int w = tid >> 6, l15 = tid & 15, g = (tid & 63) >> 4;
  const f32x4 zero4 = {0.f, 0.f, 0.f, 0.f};

  if (tid < 256) {
    int j = tid >> 3, ii = tid & 7;
    ((u32*)Vt)[j * 66 + 56 + ii] = 0;
  }

  // ---- P1: [Q|K|V] = x @ W^T, 3-term hi/lo MFMA; x + W frags direct from global
  if (w < 6) {
    const int mi = w >> 1, half = w & 1;
    const int j = 16 * half + l15;
    const float* Wp = (mi == 0) ? Wq : (mi == 1) ? Wk : Wv;
    float bias = (mi == 0) ? bq[j] : (mi == 1) ? bk[j] : bv[j];
    s16x8 bhf[2], blf[2];
#pragma unroll
    for (int kt = 0; kt < 2; ++kt)
      hilo8(Wp + j * 64 + kt * 32 + g * 8, true, bhf[kt], blf[kt]);
    const float* xb = x + (size_t)b * 6400;
#pragma unroll
    for (int tm = 0; tm < 7; ++tm) {
      const int arow = 16 * tm + l15;
      f32x4 acc = zero4;
#pragma unroll
      for (int kt = 0; kt < 2; ++kt) {
        s16x8 ah, al;
        hilo8(xb + arow * 64 + kt * 32 + g * 8, arow < 100, ah, al);
        acc = mfma16(al, bhf[kt], acc);
        acc = mfma16(ah, blf[kt], acc);
        acc = mfma16(ah, bhf[kt], acc);
      }
      const int row0 = 16 * tm + 4 * g;
#pragma unroll
      for (int r = 0; r < 4; ++r) {
        int row = row0 + r;
        float v = acc[r] + bias;
        if (mi == 0)      Qs[row * 36 + j] = f2b(v);
        else if (mi == 1) Ks[row * 36 + j] = f2b(v);
        else              Vt[j * 132 + row] = f2b(v);   // transposed; rows>=100 = bias (A=0 there)
      }
    }
  }
  __syncthreads();

  // ---- P2: S = Q K^T (MFMA), softmax -> A single-bf16 [112][132]
  if (w < 7) {
    const int tm = w;
    s16x8 aq = *(const s16x8*)&Qs[(16 * tm + l15) * 36 + g * 8];
    f32x4 sc[7];
#pragma unroll
    for (int tn = 0; tn < 7; ++tn) {
      s16x8 bb = *(const s16x8*)&Ks[(16 * tn + l15) * 36 + g * 8];
      sc[tn] = mfma16(aq, bb, zero4);
    }
    const int row0 = 16 * tm + 4 * g;
#pragma unroll
    for (int r = 0; r < 4; ++r) {
      const int row = row0 + r;
      float v[7];
#pragma unroll
      for (int tn = 0; tn < 7; ++tn) v[tn] = sc[tn][r];
      if (l15 >= 4) v[6] = -3.0e38f;               // mask cols >= 100
      float m = v[0];
#pragma unroll
      for (int tn = 1; tn < 7; ++tn) m = fmaxf(m, v[tn]);
#pragma unroll
      for (int off = 1; off < 16; off <<= 1) m = fmaxf(m, __shfl_xor(m, off, 16));
      float e[7], s = 0.f;
#pragma unroll
      for (int tn = 0; tn < 7; ++tn) { e[tn] = __expf((v[tn] - m) * 0.03125f); s += e[tn]; }
#pragma unroll
      for (int off = 1; off < 16; off <<= 1) s += __shfl_xor(s, off, 16);
      float rr = __builtin_amdgcn_rcpf(s);
      bool ok = row < 100;
#pragma unroll
      for (int tn = 0; tn < 7; ++tn) {
        float a = ok ? e[tn] * rr : 0.f;
        A16[row * 132 + 16 * tn + l15] = f2b(a);
      }
      if (l15 < 8) ((u32*)A16)[row * 66 + 56 + l15] = 0;   // cols 112..127 := 0
    }
  }
  __syncthreads();

  // ---- P3: feat = A @ V (MFMA, K=128); row-normalize -> chat hi/lo (overlay Q/K)
  if (w < 7) {
    const int tm = w;
    f32x4 f0 = zero4, f1 = zero4;
#pragma unroll
    for (int kt = 0; kt < 4; ++kt) {
      s16x8 a   = *(const s16x8*)&A16[(16 * tm + l15) * 132 + kt * 32 + g * 8];
      s16x8 b0  = *(const s16x8*)&Vt[l15 * 132 + kt * 32 + g * 8];
      s16x8 b1v = *(const s16x8*)&Vt[(16 + l15) * 132 + kt * 32 + g * 8];
      f0 = mfma16(a, b0, f0);
      f1 = mfma16(a, b1v, f1);
    }
    const int row0 = 16 * tm + 4 * g;
#pragma unroll
    for (int r = 0; r < 4; ++r) {
      float v0 = f0[r], v1 = f1[r];
      float s = v0 + v1;
#pragma unroll
      for (int off = 1; off < 16; off <<= 1) s += __shfl_xor(s, off, 16);
      float mean = s * 0.03125f;
      float xc0 = v0 - mean, xc1 = v1 - mean;
      float q = xc0 * xc0 + xc1 * xc1;
#pragma unroll
      for (int off = 1; off < 16; off <<= 1) q += __shfl_xor(q, off, 16);
      float inv = rsqrtf(q + 1e-30f);              // zero rows stay exactly 0
      const int row = row0 + r;
      float c0 = xc0 * inv, c1 = xc1 * inv;
      u16 h0 = f2b(c0), h1 = f2b(c1);
      chh[row * 36 + l15]      = h0;
      chh[row * 36 + 16 + l15] = h1;
      chl[row * 36 + l15]      = f2b(c0 - b2f(h0));
      chl[row * 36 + 16 + l15] = f2b(c1 - b2f(h1));
    }
  }
  __syncthreads();

  // ---- P4: corr = clip(3-term chat@chat^T) -> HBM bf16 (from regs, no LDS)
  if (w < 7) {
    u16* cgu = (u16*)(corr_g + (size_t)b * 10000);
    const int tm = w;
    s16x8 ah = *(const s16x8*)&chh[(16 * tm + l15) * 36 + g * 8];
    s16x8 al = *(const s16x8*)&chl[(16 * tm + l15) * 36 + g * 8];
    const int row0 = 16 * tm + 4 * g;
#pragma unroll
    for (int tn = 0; tn < 7; ++tn) {
      s16x8 bh = *(const s16x8*)&chh[(16 * tn + l15) * 36 + g * 8];
      s16x8 bl = *(const s16x8*)&chl[(16 * tn + l15) * 36 + g * 8];
      f32x4 c = mfma16(al, bh, zero4);
      c = mfma16(ah, bl, c);
      c = mfma16(ah, bh, c);
      const int col = 16 * tn + l15;
      if (col < 100) {
#pragma unroll
        for (int r = 0; r < 4; ++r) {
          const int row = row0 + r;
          if (row < 100)
            cgu[row * 100 + col] = f2b(fminf(1.f, fmaxf(-1.f, c[r])));
        }
      }
    }
  }
}

// ---------------- KB0 (R14): coalesced x->LDS, t0 MFMA from LDS, corr overlay, z1 ----------------
// LDS: xs f32[112][68] @0 (30464B; clLu u32[100][50] overlays after P1) ; tL f32[100][33] @30464
// total 43664B -> 3 blocks/CU.
__global__ __launch_bounds__(256, 3) void kb0_kernel(
    const float* __restrict__ x,
    const __hip_bfloat16* __restrict__ corr_g,
    const float* __restrict__ W1, const float* __restrict__ b1,
    float* __restrict__ stats_out,
    float* __restrict__ zout)                      // z1 [B,100,32]
{
  __shared__ __align__(16) char smem[43664];
  float* xs   = (float*)smem;                      // [112][68]
  u32*   clLu = (u32*)smem;                        // [100][50] overlay (P2+)
  float* tL   = (float*)(smem + 30464);            // [100][33]

  const int b = blockIdx.x, tid = threadIdx.x;
  const int w = tid >> 6, l15 = tid & 15, g = (tid & 63) >> 4;
  const f32x4 zero4 = {0.f, 0.f, 0.f, 0.f};

  // W1 frags from global (8KB, L2-hot) -- issued before staging so loads overlap
  s16x8 bhf[2][2], blf[2][2];                      // [j-half][kt]
#pragma unroll
  for (int half = 0; half < 2; ++half) {
    const int j = 16 * half + l15;
#pragma unroll
    for (int kt = 0; kt < 2; ++kt)
      hilo8(W1 + j * 64 + kt * 32 + g * 8, true, bhf[half][kt], blf[half][kt]);
  }

  // ---- P0: stage x coalesced float4 -> xs [112][68]; rows >= 100 zeroed
  {
    const float4* xg4 = (const float4*)(x + (size_t)b * 6400);
    for (int i = tid; i < 112 * 16; i += 256) {
      int r = i >> 4, c4 = i & 15;
      float4 v = {0.f, 0.f, 0.f, 0.f};
      if (r < 100) v = xg4[r * 16 + c4];
      *(float4*)&xs[r * 68 + c4 * 4] = v;
    }
  }
  __syncthreads();

  // ---- P1: t0 = x @ W1^T via 3-term hi/lo MFMA; x frags from LDS
  {
#pragma unroll
    for (int t2 = 0; t2 < 2; ++t2) {
      const int tm = w + 4 * t2;
      if (tm < 7) {
        const int arow = 16 * tm + l15;
        s16x8 ah[2], al[2];
#pragma unroll
        for (int kt = 0; kt < 2; ++kt)
          hilo8_lds(&xs[arow * 68 + kt * 32 + g * 8], ah[kt], al[kt]);
        const int row0 = 16 * tm + 4 * g;
#pragma unroll
        for (int half = 0; half < 2; ++half) {
          f32x4 acc = zero4;
#pragma unroll
          for (int kt = 0; kt < 2; ++kt) {
            acc = mfma16(al[kt], bhf[half][kt], acc);
            acc = mfma16(ah[kt], blf[half][kt], acc);
            acc = mfma16(ah[kt], bhf[half][kt], acc);
          }
          const int j = 16 * half + l15;
#pragma unroll
          for (int r = 0; r < 4; ++r) {
            int row = row0 + r;
            if (row < 100) tL[row * 33 + j] = acc[r];
          }
        }
      }
    }
  }
  __syncthreads();

  // ---- P2: corr -> clLu (overlays xs; coalesced u32)
  {
    const u32* cgu = (const u32*)(corr_g + (size_t)b * 10000);
    for (int i = tid; i < 5000; i += 256) {
      int n = (i * 5243) >> 18;                    // i/50 for i<5000
      int mm = i - n * 50;
      clLu[n * 50 + mm] = cgu[i];
    }
  }
  __syncthreads();

  // ---- P3: z1 = corr @ t0 + b1 ; stats (proven VALU form)
  {
    const int j  = tid & 31;
    const int nb = tid >> 5;
    float acc[13];
    float bj = b1[j];
#pragma unroll
    for (int k = 0; k < 13; ++k) acc[k] = bj;
    int nrow[13];
#pragma unroll
    for (int k = 0; k < 13; ++k) nrow[k] = min(nb + k * 8, 99);
#pragma unroll 5
    for (int m4 = 0; m4 < 25; ++m4) {
      float ta = tL[(m4 * 4 + 0) * 33 + j];
      float tb = tL[(m4 * 4 + 1) * 33 + j];
      float tc = tL[(m4 * 4 + 2) * 33 + j];
      float td = tL[(m4 * 4 + 3) * 33 + j];
#pragma unroll
      for (int k = 0; k < 13; ++k) {
        u32 p0 = clLu[nrow[k] * 50 + 2 * m4];
        u32 p1 = clLu[nrow[k] * 50 + 2 * m4 + 1];
        acc[k] = fmaf(blo(p0), ta, fmaf(bhi(p0), tb,
                 fmaf(blo(p1), tc, fmaf(bhi(p1), td, acc[k]))));
      }
    }
    float* zo = zout + (size_t)b * 3200;
#pragma unroll
    for (int k = 0; k < 13; ++k) {
      int n = nb + k * 8;
      if (n < 100) {
        float v = acc[k];
        zo[n * 32 + j] = v;
        float s = v, ss = v * v;
#pragma unroll
        for (int off = 16; off; off >>= 1) {
          s  += __shfl_xor(s, off, 32);
          ss += __shfl_xor(ss, off, 32);
        }
        if (j == 0) {
          atomicAdd(&stats_out[n], s);
          atomicAdd(&stats_out[100 + n], ss);
        }
      }
    }
  }
}

// ---------------- KB: GCN step; corr bf16-in-LDS [100][50] -> 40.8KB, 4 blocks/CU ----------------
template<int FIN, int FOUT>
__global__ __launch_bounds__(256, 4) void kb_kernel(
    const float* __restrict__ zin,
    const __hip_bfloat16* __restrict__ corr_g,
    const float* __restrict__ W, const float* __restrict__ bias,
    const float* __restrict__ stats_in, float* __restrict__ stats_out,
    float* __restrict__ zout)
{
  constexpr int LOGF  = (FOUT == 16) ? 4 : (FOUT == 8) ? 3 : (FOUT == 4) ? 2 : 1;
  constexpr int LOGFI = (FIN == 32) ? 5 : (FIN == 16) ? 4 : (FIN == 8) ? 3 : 2;
  constexpr int RP = 256 / FOUT;
  constexpr int NR = (100 + RP - 1) / RP;

  __shared__ u32 clLu[100 * 50];
  __shared__ float mS[100], vS[100];
  __shared__ float hL[100 * 33];
  __shared__ float tL[100 * (FOUT + 1)];

  const int b = blockIdx.x, tid = threadIdx.x;

  {
    const u32* cgu = (const u32*)(corr_g + (size_t)b * 10000);
    for (int i = tid; i < 5000; i += 256) {
      int n = (i * 5243) >> 18;
      int mm = i - n * 50;
      clLu[n * 50 + mm] = cgu[i];
    }
  }
  if (tid < 100) {
    float cnt  = 8192.0f * (float)FIN;
    float mean = stats_in[tid] / cnt;
    float var  = stats_in[100 + tid] / cnt - mean * mean;
    mS[tid] = mean;
    vS[tid] = rsqrtf(var + 1e-5f);
  }
  __syncthreads();

  {
    const float4* zb4 = (const float4*)(zin + (size_t)b * 100 * FIN);
    for (int i4 = tid; i4 < 25 * FIN; i4 += 256) {
      int n = i4 >> (LOGFI - 2);
      int c = (i4 << 2) & (FIN - 1);
      float4 z = zb4[i4];
      float mn = mS[n], iv = vS[n];
      hL[n * 33 + c + 0] = fast_tanh((z.x - mn) * iv);
      hL[n * 33 + c + 1] = fast_tanh((z.y - mn) * iv);
      hL[n * 33 + c + 2] = fast_tanh((z.z - mn) * iv);
      hL[n * 33 + c + 3] = fast_tanh((z.w - mn) * iv);
    }
  }
  __syncthreads();

  const int j  = tid & (FOUT - 1);
  const int nb = tid >> LOGF;

  {
    float wreg[FIN];
#pragma unroll
    for (int c = 0; c < FIN; ++c) wreg[c] = W[j * FIN + c];
#pragma unroll
    for (int k = 0; k < NR; ++k) {
      int n = nb + k * RP;
      if (n < 100) {
        float a = 0.f;
#pragma unroll
        for (int c = 0; c < FIN; ++c) a = fmaf(hL[n * 33 + c], wreg[c], a);
        tL[n * (FOUT + 1) + j] = a;
      }
    }
  }
  __syncthreads();

  {
    float acc[NR];
    float bj = bias[j];
#pragma unroll
    for (int k = 0; k < NR; ++k) acc[k] = bj;
    int nrow[NR];
#pragma unroll
    for (int k = 0; k < NR; ++k) nrow[k] = min(nb + k * RP, 99);
#pragma unroll 5
    for (int m4 = 0; m4 < 25; ++m4) {
      float ta = tL[(m4 * 4 + 0) * (FOUT + 1) + j];
      float tb = tL[(m4 * 4 + 1) * (FOUT + 1) + j];
      float tc = tL[(m4 * 4 + 2) * (FOUT + 1) + j];
      float td = tL[(m4 * 4 + 3) * (FOUT + 1) + j];
#pragma unroll
      for (int k = 0; k < NR; ++k) {
        u32 p0 = clLu[nrow[k] * 50 + 2 * m4];
        u32 p1 = clLu[nrow[k] * 50 + 2 * m4 + 1];
        acc[k] = fmaf(blo(p0), ta, fmaf(bhi(p0), tb,
                 fmaf(blo(p1), tc, fmaf(bhi(p1), td, acc[k]))));
      }
    }
    float* zo = zout + (size_t)b * 100 * FOUT;
#pragma unroll
    for (int k = 0; k < NR; ++k) {
      int n = nb + k * RP;
      if (n < 100) {
        float v = acc[k];
        zo[n * FOUT + j] = v;
        float s = v, ss = v * v;
#pragma unroll
        for (int off = FOUT >> 1; off; off >>= 1) {
          s  += __shfl_xor(s, off, FOUT);
          ss += __shfl_xor(ss, off, FOUT);
        }
        if (j == 0) {
          atomicAdd(&stats_out[n], s);
          atomicAdd(&stats_out[100 + n], ss);
        }
      }
    }
  }
}

// ---------------- KF: final BN+tanh + [200]->[2] head ----------------
__global__ __launch_bounds__(256) void kf_kernel(
    const float* __restrict__ z5, const float* __restrict__ stats5,
    const float* __restrict__ Wf, const float* __restrict__ bfv,
    float* __restrict__ out)
{
  __shared__ float mS[100], vS[100];
  const int tid = threadIdx.x;
  if (tid < 100) {
    float cnt  = 8192.0f * 2.0f;
    float mean = stats5[tid] / cnt;
    float var  = stats5[100 + tid] / cnt - mean * mean;
    mS[tid] = mean;
    vS[tid] = rsqrtf(var + 1e-5f);
  }
  __syncthreads();
  const int wvid = tid >> 6, lane = tid & 63;
  const int b = blockIdx.x * 4 + wvid;
  const float* zb = z5 + (size_t)b * 200;
  float a0 = 0.f, a1 = 0.f;
#pragma unroll
  for (int p = 0; p < 4; ++p) {
    int jj = lane + p * 64;
    if (jj < 200) {
      int n = jj >> 1;
      float hv = fast_tanh((zb[jj] - mS[n]) * vS[n]);
      a0 = fmaf(hv, Wf[jj], a0);
      a1 = fmaf(hv, Wf[200 + jj], a1);
    }
  }
#pragma unroll
  for (int off = 32; off; off >>= 1) {
    a0 += __shfl_xor(a0, off, 64);
    a1 += __shfl_xor(a1, off, 64);
  }
  if (lane == 0) {
    out[b * 2 + 0] = a0 + bfv[0];
    out[b * 2 + 1] = a1 + bfv[1];
  }
}

extern "C" void kernel_launch(void* const* d_in, const int* in_sizes, int n_in,
                              void* d_out, int out_size, void* d_ws, size_t ws_size,
                              hipStream_t stream)
{
  const float* x  = (const float*)d_in[0];
  const float* Wq = (const float*)d_in[1];
  const float* bq = (const float*)d_in[2];
  const float* Wk = (const float*)d_in[3];
  const float* bk = (const float*)d_in[4];
  const float* Wv = (const float*)d_in[5];
  const float* bv = (const float*)d_in[6];
  const float* W1 = (const float*)d_in[7];
  const float* b1 = (const float*)d_in[8];
  const float* W2 = (const float*)d_in[9];
  const float* b2 = (const float*)d_in[10];
  const float* W3 = (const float*)d_in[11];
  const float* b3 = (const float*)d_in[12];
  const float* W4 = (const float*)d_in[13];
  const float* b4 = (const float*)d_in[14];
  const float* W5 = (const float*)d_in[15];
  const float* b5 = (const float*)d_in[16];
  const float* Wf = (const float*)d_in[17];
  const float* bf = (const float*)d_in[18];
  float* out = (float*)d_out;

  char* ws = (char*)d_ws;
  // ws: corr bf16 [8192,100,100] @0 ; zA f32 [8192,100,32] @163840000 ;
  //     zB f32 [8192,100,16] @268697600 ; stats 5*[200] f32 @321126400
  const size_t NEED = 321130400ull;
  if (ws_size < NEED) return;

  __hip_bfloat16* corr_g = (__hip_bfloat16*)ws;
  float* zA    = (float*)(ws + 163840000ull);
  float* zB    = (float*)(ws + 268697600ull);
  float* stats = (float*)(ws + 321126400ull);

  (void)hipMemsetAsync(stats, 0, 5 * 200 * sizeof(float), stream);

  ka_kernel<<<8192, 512, 0, stream>>>(x, Wq, bq, Wk, bk, Wv, bv, corr_g);
  kb0_kernel<<<8192, 256, 0, stream>>>(x, corr_g, W1, b1, stats, zA);
  kb_kernel<32, 16><<<8192, 256, 0, stream>>>(zA, corr_g, W2, b2, stats,       stats + 200, zB);
  kb_kernel<16,  8><<<8192, 256, 0, stream>>>(zB, corr_g, W3, b3, stats + 200, stats + 400, zA);
  kb_kernel< 8,  4><<<8192, 256, 0, stream>>>(zA, corr_g, W4, b4, stats + 400, stats + 600, zB);
  kb_kernel< 4,  2><<<8192, 256, 0, stream>>>(zB, corr_g, W5, b5, stats + 600, stats + 800, zA);
  kf_kernel<<<2048, 256, 0, stream>>>(zA, stats + 800, Wf, bf, out);
}